// Round 26
// baseline (107.262 us; speedup 1.0000x reference)
//
#include <hip/hip_runtime.h>
#include <hip/hip_bf16.h>
#include <stdint.h>

#define NN 4096
#define NT 32                      // 128-wide tiles per side
#define SLOTS_PER_XCD 132          // max jobs per XCD group (x=0)
#define GRID_TOT (8 * SLOTS_PER_XCD)

typedef __attribute__((ext_vector_type(8))) __bf16 bf16x8;
typedef __attribute__((ext_vector_type(8))) short  s16x8;
typedef __attribute__((ext_vector_type(4))) float  f32x4;

__device__ __forceinline__ ushort f2bf(float f) {
    uint32_t u = __builtin_bit_cast(uint32_t, f);
    u += 0x7fffu + ((u >> 16) & 1u);            // RNE to bf16
    return (ushort)(u >> 16);
}

// jobs in column bj: sum_{m=1}^{bj+1} ceil(m/8)
__device__ __forceinline__ int col_jobs(int bj) {
    int L = bj + 1, a = L >> 3, b = L & 7;
    return 4 * a * (a + 1) + b * (a + 1);
}

// ---------- fused prep (r24): z=0 conv A (triu, bf16), z=1 conv B^T (triu, bf16), z=2 zero C tiles ----------
__global__ __launch_bounds__(256) void prep(const float* __restrict__ A,
                                            const float* __restrict__ B,
                                            ushort* __restrict__ Au,
                                            ushort* __restrict__ BTu,
                                            float* __restrict__ C) {
    const int role = blockIdx.z;
    const int tr = blockIdx.y;
    const int tc = blockIdx.x;
    const int tid = threadIdx.x;

    if (role == 0) {
        if (tc < tr) return;                     // lower A-tiles never read
        const bool diag = (tc == tr);
#pragma unroll
        for (int q = 0; q < 8; ++q) {
            int g = q * 256 + tid;
            int r = g >> 4, c0 = (g & 15) << 3;
            int row = tr * 128 + r, col0 = tc * 128 + c0;
            const float* p = A + (size_t)row * NN + col0;
            f32x4 a0 = *reinterpret_cast<const f32x4*>(p);
            f32x4 a1 = *reinterpret_cast<const f32x4*>(p + 4);
            s16x8 o;
#pragma unroll
            for (int j = 0; j < 8; ++j) {
                float f = (j < 4) ? a0[j] : a1[j - 4];
                if (diag && (col0 + j) < row) f = 0.0f;
                o[j] = (short)f2bf(f);
            }
            *reinterpret_cast<s16x8*>(Au + (size_t)row * NN + col0) = o;
        }
        return;
    }

    if (role == 1) {
        // BTu[j][k] = (j >= k) ? bf16(B[k][j]) : 0 ; tr = k-tile, tc = j-tile
        if (tc < tr) return;
        const bool diag = (tc == tr);
        __shared__ ushort tile[128][129];        // pad 129: transpose read 2-way (free)
#pragma unroll
        for (int q = 0; q < 8; ++q) {
            int g = q * 256 + tid;               // 2048 groups of 8 floats (32B/thread)
            int r = g >> 4, c0 = (g & 15) << 3;
            int krow = tr * 128 + r;
            const float* p = B + (size_t)krow * NN + tc * 128 + c0;
            f32x4 v0 = *reinterpret_cast<const f32x4*>(p);
            f32x4 v1 = *reinterpret_cast<const f32x4*>(p + 4);
#pragma unroll
            for (int j = 0; j < 8; ++j) {
                int col = c0 + j;
                float f = (j < 4) ? v0[j] : v1[j - 4];
                if (diag && (tc * 128 + col) < krow) f = 0.0f;
                tile[r][col] = f2bf(f);
            }
        }
        __syncthreads();
#pragma unroll
        for (int q = 0; q < 8; ++q) {
            int g = q * 256 + tid;
            int orow = g >> 4, ch = g & 15;
            s16x8 o;
#pragma unroll
            for (int j = 0; j < 8; ++j) o[j] = (short)tile[ch * 8 + j][orow];
            *reinterpret_cast<s16x8*>(BTu + (size_t)(tc * 128 + orow) * NN + tr * 128 + ch * 8) = o;
        }
        return;
    }

    // role 2 (r24): zero C tile if lower-tri OR multi-chunk upper tile (d >= 8 -> atomics)
    {
        int d = tc - tr;
        bool need = (d < 0) || (d >= 8);
        if (!need) return;
        int r = tid >> 1, cb = (tid & 1) * 64;
        float* p = C + (size_t)(tr * 128 + r) * NN + tc * 128 + cb;
        f32x4 z = {0.f, 0.f, 0.f, 0.f};
#pragma unroll
        for (int v = 0; v < 16; ++v) *reinterpret_cast<f32x4*>(p + v * 4) = z;
    }
}

// ---------------- MAIN: 128x128, BK=128, 2-deep counted-vmcnt, 128KB dynamic LDS ----------------
// r26: extend r24's validated lever (fewer barrier rendezvous: BK 32->64 = -10%) to BK=128 —
// barriers/k-tile 4->2. Step = 4 K=32 halves from one read-only buffer (no inner barriers).
// Swizzle for 256B rows: chunk g -> row=g>>4, slot s=g&15 sources kslot s^(row&15); read kslot
// k'=h*4+kh at slot k'^(row&15): 16 lanes -> 16 distinct slots -> 2-way/bank = free.
// 1 block/CU (128KB LDS); in-loop vmcnt(16) (next stage's 16 loads stay in flight), 0 only at end.
__global__ __launch_bounds__(256, 1) void trimm_big(const ushort* __restrict__ Au,
                                                    const ushort* __restrict__ BTu,
                                                    float* __restrict__ C) {
    extern __shared__ ushort lds[];              // [4][16384]: A0,A1,B0,B1
    const int tid = threadIdx.x;
    const int xcd = blockIdx.x & 7;
    int slot = blockIdx.x >> 3;

    // ---- decode (xcd, slot) -> (bi, bj, chunk c of nch) ---- (r24 verbatim)
    const int cols[4] = {31 - xcd, 16 + xcd, 15 - xcd, xcd};
    int bj = -1;
    for (int ci = 0; ci < 4; ++ci) {
        int cj = cols[ci], n = col_jobs(cj);
        if (slot < n) { bj = cj; break; }
        slot -= n;
    }
    if (bj < 0) return;

    int bi = 0, c = 0, nch = 1;
    for (int i = 0; i <= bj; ++i) {
        int nc = (bj - i + 8) >> 3;
        if (slot < nc) { bi = i; c = slot; nch = nc; break; }
        slot -= nc;
    }
    const int d = bj - bi;
    const int L = d + 1;
    const int kt0 = (c * L) / nch, kt1 = ((c + 1) * L) / nch;
    const int k_base = (bi + kt0) * 128;
    const int nsteps = kt1 - kt0;                // BK=128 steps (1..8)

    const int wid = tid >> 6, lane = tid & 63;
    const int wr = wid >> 1, wc = wid & 1;
    const int l16 = lane & 15, kh = lane >> 4;

    // staging: 2048 chunks/operand/stage; thread does g = q*256+tid, q=0..7.
    // chunk g -> LDS ushort offset g*8 (row=g>>4, slot=g&15); source kslot = (g&15)^((g>>4)&15)
    const ushort* pA[8];
    const ushort* pB[8];
    int lo[8];
#pragma unroll
    for (int q = 0; q < 8; ++q) {
        int g = q * 256 + tid;
        int row = g >> 4;
        int ks = ((g & 15) ^ (row & 15)) << 3;
        pA[q] = Au  + (size_t)(bi * 128 + row) * NN + ks + k_base;
        pB[q] = BTu + (size_t)(bj * 128 + row) * NN + ks + k_base;
        lo[q] = g * 8;
    }

#define GLOAD(src, dst) __builtin_amdgcn_global_load_lds(                      \
        (const __attribute__((address_space(1))) void*)(src),                  \
        (__attribute__((address_space(3))) void*)(dst), 16, 0, 0)
#define STAGE(buf, off)                                                        \
    do {                                                                       \
        ushort* _a = lds + (buf) * 16384;                                      \
        ushort* _b = lds + 32768 + (buf) * 16384;                              \
        _Pragma("unroll")                                                      \
        for (int _q = 0; _q < 8; ++_q) {                                       \
            GLOAD(pA[_q] + (off), _a + lo[_q]);                                \
            GLOAD(pB[_q] + (off), _b + lo[_q]);                                \
        }                                                                      \
    } while (0)

    f32x4 zero = {0.f, 0.f, 0.f, 0.f};
    f32x4 acc[4][4];
#pragma unroll
    for (int m = 0; m < 4; ++m)
#pragma unroll
        for (int n = 0; n < 4; ++n) acc[m][n] = zero;

    // prologue: 2 stages in flight (16 loads each)
    STAGE(0, 0);
    if (nsteps > 1) STAGE(1, 128);

    for (int t = 0; t < nsteps; ++t) {
        const int cur = t & 1;
        // wait for stage t only: stage t+1's 16 loads stay outstanding (never 0 in-loop)
        if (t + 1 < nsteps) asm volatile("s_waitcnt vmcnt(16)" ::: "memory");
        else                asm volatile("s_waitcnt vmcnt(0)" ::: "memory");
        __builtin_amdgcn_s_barrier();
        __builtin_amdgcn_sched_barrier(0);   // pin ds_reads below the barrier (cross-wave staging)

        const ushort* Ab = lds + cur * 16384;
        const ushort* Bb = lds + 32768 + cur * 16384;

        // four K=32 halves from the same buffer (no barrier between: read-only)
#pragma unroll
        for (int h = 0; h < 4; ++h) {
            bf16x8 af[4], bfr[4];
#pragma unroll
            for (int m = 0; m < 4; ++m) {
                int row = wr * 64 + m * 16 + l16;
                af[m] = *reinterpret_cast<const bf16x8*>(
                    &Ab[row * 128 + (((h * 4 + kh) ^ (row & 15)) << 3)]);
            }
#pragma unroll
            for (int n = 0; n < 4; ++n) {
                int row = wc * 64 + n * 16 + l16;
                bfr[n] = *reinterpret_cast<const bf16x8*>(
                    &Bb[row * 128 + (((h * 4 + kh) ^ (row & 15)) << 3)]);
            }
#pragma unroll
            for (int m = 0; m < 4; ++m)
#pragma unroll
                for (int n = 0; n < 4; ++n)
                    acc[m][n] = __builtin_amdgcn_mfma_f32_16x16x32_bf16(af[m], bfr[n], acc[m][n], 0, 0, 0);
        }

        __builtin_amdgcn_s_barrier();        // all waves done reading buf[cur]
        __builtin_amdgcn_sched_barrier(0);   // pin the overwrite below the barrier
        if (t + 2 < nsteps) STAGE(cur, (t + 2) * 128);
    }
#undef STAGE
#undef GLOAD

    // C/D layout: col = lane&15, row = (lane>>4)*4 + reg
    if (nch == 1) {
#pragma unroll
        for (int m = 0; m < 4; ++m)
#pragma unroll
            for (int n = 0; n < 4; ++n) {
                int row = bi * 128 + wr * 64 + m * 16 + kh * 4;
                int col = bj * 128 + wc * 64 + n * 16 + l16;
#pragma unroll
                for (int r = 0; r < 4; ++r)
                    C[(size_t)(row + r) * NN + col] = acc[m][n][r];
            }
    } else {
#pragma unroll
        for (int m = 0; m < 4; ++m)
#pragma unroll
            for (int n = 0; n < 4; ++n) {
                int row = bi * 128 + wr * 64 + m * 16 + kh * 4;
                int col = bj * 128 + wc * 64 + n * 16 + l16;
#pragma unroll
                for (int r = 0; r < 4; ++r)
                    unsafeAtomicAdd(&C[(size_t)(row + r) * NN + col], acc[m][n][r]);
            }
    }
}

// ---------------- FALLBACK (r24 verbatim): BK=64 static-LDS kernel ----------------
__global__ __launch_bounds__(256) void trimm_split(const ushort* __restrict__ Au,
                                                   const ushort* __restrict__ BTu,
                                                   float* __restrict__ C) {
    const int tid = threadIdx.x;
    const int xcd = blockIdx.x & 7;
    int slot = blockIdx.x >> 3;

    const int cols[4] = {31 - xcd, 16 + xcd, 15 - xcd, xcd};
    int bj = -1;
    for (int ci = 0; ci < 4; ++ci) {
        int cj = cols[ci], n = col_jobs(cj);
        if (slot < n) { bj = cj; break; }
        slot -= n;
    }
    if (bj < 0) return;

    int bi = 0, c = 0, nch = 1;
    for (int i = 0; i <= bj; ++i) {
        int nc = (bj - i + 8) >> 3;
        if (slot < nc) { bi = i; c = slot; nch = nc; break; }
        slot -= nc;
    }
    const int d = bj - bi;
    const int L = d + 1;
    const int kt0 = (c * L) / nch, kt1 = ((c + 1) * L) / nch;
    const int k_base = (bi + kt0) * 128;
    const int nsteps = (kt1 - kt0) * 2;

    __shared__ ushort lA[2][128 * 64];
    __shared__ ushort lB[2][128 * 64];

    const int wid = tid >> 6, lane = tid & 63;
    const int wr = wid >> 1, wc = wid & 1;
    const int l16 = lane & 15, kh = lane >> 4;

    const int gq0 = 0 * 256 + tid, gq1 = 1 * 256 + tid, gq2 = 2 * 256 + tid, gq3 = 3 * 256 + tid;
#define KS(g) (((((g) & 7) ^ (((g) >> 3) & 7))) << 3)
#define RW(g) ((g) >> 3)
    const ushort* pA0 = Au  + (size_t)(bi * 128 + RW(gq0)) * NN + KS(gq0) + k_base;
    const ushort* pA1 = Au  + (size_t)(bi * 128 + RW(gq1)) * NN + KS(gq1) + k_base;
    const ushort* pA2 = Au  + (size_t)(bi * 128 + RW(gq2)) * NN + KS(gq2) + k_base;
    const ushort* pA3 = Au  + (size_t)(bi * 128 + RW(gq3)) * NN + KS(gq3) + k_base;
    const ushort* pB0 = BTu + (size_t)(bj * 128 + RW(gq0)) * NN + KS(gq0) + k_base;
    const ushort* pB1 = BTu + (size_t)(bj * 128 + RW(gq1)) * NN + KS(gq1) + k_base;
    const ushort* pB2 = BTu + (size_t)(bj * 128 + RW(gq2)) * NN + KS(gq2) + k_base;
    const ushort* pB3 = BTu + (size_t)(bj * 128 + RW(gq3)) * NN + KS(gq3) + k_base;
#undef KS
#undef RW
    const int lo0 = gq0 * 8, lo1 = gq1 * 8, lo2 = gq2 * 8, lo3 = gq3 * 8;

#define GLOAD(src, dst) __builtin_amdgcn_global_load_lds(                      \
        (const __attribute__((address_space(1))) void*)(src),                  \
        (__attribute__((address_space(3))) void*)(dst), 16, 0, 0)
#define STAGE(buf, off)                                                        \
    do {                                                                       \
        GLOAD(pA0 + (off), &lA[buf][lo0]); GLOAD(pA1 + (off), &lA[buf][lo1]);  \
        GLOAD(pA2 + (off), &lA[buf][lo2]); GLOAD(pA3 + (off), &lA[buf][lo3]);  \
        GLOAD(pB0 + (off), &lB[buf][lo0]); GLOAD(pB1 + (off), &lB[buf][lo1]);  \
        GLOAD(pB2 + (off), &lB[buf][lo2]); GLOAD(pB3 + (off), &lB[buf][lo3]);  \
    } while (0)

    f32x4 zero = {0.f, 0.f, 0.f, 0.f};
    f32x4 acc[4][4];
#pragma unroll
    for (int m = 0; m < 4; ++m)
#pragma unroll
        for (int n = 0; n < 4; ++n) acc[m][n] = zero;

    STAGE(0, 0);
    if (nsteps > 1) STAGE(1, 64);

    for (int t = 0; t < nsteps; ++t) {
        const int cur = t & 1;
        if (t + 1 < nsteps) asm volatile("s_waitcnt vmcnt(8)" ::: "memory");
        else                asm volatile("s_waitcnt vmcnt(0)" ::: "memory");
        __builtin_amdgcn_s_barrier();
        __builtin_amdgcn_sched_barrier(0);

#pragma unroll
        for (int h = 0; h < 2; ++h) {
            bf16x8 af[4], bfr[4];
#pragma unroll
            for (int m = 0; m < 4; ++m) {
                int row = wr * 64 + m * 16 + l16;
                af[m] = *reinterpret_cast<const bf16x8*>(
                    &lA[cur][row * 64 + (((h * 4 + kh) ^ (row & 7)) << 3)]);
            }
#pragma unroll
            for (int n = 0; n < 4; ++n) {
                int row = wc * 64 + n * 16 + l16;
                bfr[n] = *reinterpret_cast<const bf16x8*>(
                    &lB[cur][row * 64 + (((h * 4 + kh) ^ (row & 7)) << 3)]);
            }
#pragma unroll
            for (int m = 0; m < 4; ++m)
#pragma unroll
                for (int n = 0; n < 4; ++n)
                    acc[m][n] = __builtin_amdgcn_mfma_f32_16x16x32_bf16(af[m], bfr[n], acc[m][n], 0, 0, 0);
        }

        __builtin_amdgcn_s_barrier();
        __builtin_amdgcn_sched_barrier(0);
        if (t + 2 < nsteps) STAGE(cur, (t + 2) * 64);
    }
#undef STAGE
#undef GLOAD

    if (nch == 1) {
#pragma unroll
        for (int m = 0; m < 4; ++m)
#pragma unroll
            for (int n = 0; n < 4; ++n) {
                int row = bi * 128 + wr * 64 + m * 16 + kh * 4;
                int col = bj * 128 + wc * 64 + n * 16 + l16;
#pragma unroll
                for (int r = 0; r < 4; ++r)
                    C[(size_t)(row + r) * NN + col] = acc[m][n][r];
            }
    } else {
#pragma unroll
        for (int m = 0; m < 4; ++m)
#pragma unroll
            for (int n = 0; n < 4; ++n) {
                int row = bi * 128 + wr * 64 + m * 16 + kh * 4;
                int col = bj * 128 + wc * 64 + n * 16 + l16;
#pragma unroll
                for (int r = 0; r < 4; ++r)
                    unsafeAtomicAdd(&C[(size_t)(row + r) * NN + col], acc[m][n][r]);
            }
    }
}

// ---------------- fp32 fallback (only if ws too small) ----------------
__global__ __launch_bounds__(256) void tri_fp32(const float* __restrict__ A,
                                                const float* __restrict__ B,
                                                float* __restrict__ C) {
    const int bi = blockIdx.y, bj = blockIdx.x, tid = threadIdx.x;
    const int r0 = (tid >> 4) << 2, c0 = (tid & 15) << 2;
    f32x4 z = {0.f, 0.f, 0.f, 0.f};
    if (bi > bj) {
#pragma unroll
        for (int r = 0; r < 4; ++r)
            *reinterpret_cast<f32x4*>(C + (size_t)(bi * 64 + r0 + r) * NN + bj * 64 + c0) = z;
        return;
    }
    __shared__ float As[64][65], Bs[64][65];
    float acc[4][4] = {};
    for (int kt = bi; kt <= bj; ++kt) {
        const int k0 = kt * 64;
#pragma unroll
        for (int q = 0; q < 4; ++q) {
            int g = q * 256 + tid, r = g >> 4, f4 = g & 15;
            f32x4 va = *reinterpret_cast<const f32x4*>(A + (size_t)(bi * 64 + r) * NN + k0 + f4 * 4);
            f32x4 vb = *reinterpret_cast<const f32x4*>(B + (size_t)(k0 + r) * NN + bj * 64 + f4 * 4);
#pragma unroll
            for (int j = 0; j < 4; ++j) {
                As[r][f4 * 4 + j] = (k0 + f4 * 4 + j >= bi * 64 + r) ? va[j] : 0.f;
                Bs[r][f4 * 4 + j] = (bj * 64 + f4 * 4 + j >= k0 + r) ? vb[j] : 0.f;
            }
        }
        __syncthreads();
        for (int kk = 0; kk < 64; ++kk) {
#pragma unroll
            for (int r = 0; r < 4; ++r) {
                float a = As[r0 + r][kk];
#pragma unroll
                for (int cc = 0; cc < 4; ++cc) acc[r][cc] += a * Bs[kk][c0 + cc];
            }
        }
        __syncthreads();
    }
#pragma unroll
    for (int r = 0; r < 4; ++r) {
        f32x4 o = {acc[r][0], acc[r][1], acc[r][2], acc[r][3]};
        *reinterpret_cast<f32x4*>(C + (size_t)(bi * 64 + r0 + r) * NN + bj * 64 + c0) = o;
    }
}

extern "C" void kernel_launch(void* const* d_in, const int* in_sizes, int n_in,
                              void* d_out, int out_size, void* d_ws, size_t ws_size,
                              hipStream_t stream) {
    const float* A = (const float*)d_in[0];
    const float* B = (const float*)d_in[1];
    float* C = (float*)d_out;

    const size_t need = (size_t)2 * NN * NN * sizeof(ushort);   // 64 MB
    if (ws_size >= need) {
        ushort* Au  = (ushort*)d_ws;
        ushort* BTu = Au + (size_t)NN * NN;
        prep<<<dim3(32, 32, 3), 256, 0, stream>>>(A, B, Au, BTu, C);
        hipError_t e = hipFuncSetAttribute((const void*)trimm_big,
                                           hipFuncAttributeMaxDynamicSharedMemorySize, 131072);
        if (e == hipSuccess) {
            trimm_big<<<GRID_TOT, 256, 131072, stream>>>(Au, BTu, C);
        } else {
            trimm_split<<<GRID_TOT, 256, 0, stream>>>(Au, BTu, C);
        }
    } else {
        tri_fp32<<<dim3(64, 64), 256, 0, stream>>>(A, B, C);
    }
}

// Round 27
// 101.017 us; speedup vs baseline: 1.0618x; 1.0618x over previous
//
#include <hip/hip_runtime.h>
#include <hip/hip_bf16.h>
#include <stdint.h>

#define NN 4096
#define NT 32                      // 128-wide tiles per side
#define SLOTS_PER_XCD 132          // max jobs per XCD group (x=0)
#define GRID_TOT (8 * SLOTS_PER_XCD)

typedef __attribute__((ext_vector_type(8))) __bf16 bf16x8;
typedef __attribute__((ext_vector_type(8))) short  s16x8;
typedef __attribute__((ext_vector_type(4))) float  f32x4;

__device__ __forceinline__ ushort f2bf(float f) {
    uint32_t u = __builtin_bit_cast(uint32_t, f);
    u += 0x7fffu + ((u >> 16) & 1u);            // RNE to bf16
    return (ushort)(u >> 16);
}

// jobs in column bj: sum_{m=1}^{bj+1} ceil(m/8)
__device__ __forceinline__ int col_jobs(int bj) {
    int L = bj + 1, a = L >> 3, b = L & 7;
    return 4 * a * (a + 1) + b * (a + 1);
}

// ---------- fused prep: z=0 conv A (triu, bf16), z=1 conv B^T (triu, bf16), z=2 zero C tiles ----------
__global__ __launch_bounds__(256) void prep(const float* __restrict__ A,
                                            const float* __restrict__ B,
                                            ushort* __restrict__ Au,
                                            ushort* __restrict__ BTu,
                                            float* __restrict__ C) {
    const int role = blockIdx.z;
    const int tr = blockIdx.y;
    const int tc = blockIdx.x;
    const int tid = threadIdx.x;

    if (role == 0) {
        if (tc < tr) return;                     // lower A-tiles never read
        const bool diag = (tc == tr);
#pragma unroll
        for (int q = 0; q < 8; ++q) {
            int g = q * 256 + tid;
            int r = g >> 4, c0 = (g & 15) << 3;
            int row = tr * 128 + r, col0 = tc * 128 + c0;
            const float* p = A + (size_t)row * NN + col0;
            f32x4 a0 = *reinterpret_cast<const f32x4*>(p);
            f32x4 a1 = *reinterpret_cast<const f32x4*>(p + 4);
            s16x8 o;
#pragma unroll
            for (int j = 0; j < 8; ++j) {
                float f = (j < 4) ? a0[j] : a1[j - 4];
                if (diag && (col0 + j) < row) f = 0.0f;
                o[j] = (short)f2bf(f);
            }
            *reinterpret_cast<s16x8*>(Au + (size_t)row * NN + col0) = o;
        }
        return;
    }

    if (role == 1) {
        // BTu[j][k] = (j >= k) ? bf16(B[k][j]) : 0 ; tr = k-tile, tc = j-tile
        if (tc < tr) return;
        const bool diag = (tc == tr);
        __shared__ ushort tile[128][129];        // pad 129: transpose read 2-way (free)
#pragma unroll
        for (int q = 0; q < 8; ++q) {
            int g = q * 256 + tid;               // 2048 groups of 8 floats (32B/thread)
            int r = g >> 4, c0 = (g & 15) << 3;
            int krow = tr * 128 + r;
            const float* p = B + (size_t)krow * NN + tc * 128 + c0;
            f32x4 v0 = *reinterpret_cast<const f32x4*>(p);
            f32x4 v1 = *reinterpret_cast<const f32x4*>(p + 4);
#pragma unroll
            for (int j = 0; j < 8; ++j) {
                int col = c0 + j;
                float f = (j < 4) ? v0[j] : v1[j - 4];
                if (diag && (tc * 128 + col) < krow) f = 0.0f;
                tile[r][col] = f2bf(f);
            }
        }
        __syncthreads();
#pragma unroll
        for (int q = 0; q < 8; ++q) {
            int g = q * 256 + tid;
            int orow = g >> 4, ch = g & 15;
            s16x8 o;
#pragma unroll
            for (int j = 0; j < 8; ++j) o[j] = (short)tile[ch * 8 + j][orow];
            *reinterpret_cast<s16x8*>(BTu + (size_t)(tc * 128 + orow) * NN + tr * 128 + ch * 8) = o;
        }
        return;
    }

    // role 2: zero C tile if lower-tri OR multi-chunk upper tile (d >= 8 -> atomic-accumulated)
    {
        int d = tc - tr;
        bool need = (d < 0) || (d >= 8);
        if (!need) return;
        int r = tid >> 1, cb = (tid & 1) * 64;
        float* p = C + (size_t)(tr * 128 + r) * NN + tc * 128 + cb;
        f32x4 z = {0.f, 0.f, 0.f, 0.f};
#pragma unroll
        for (int v = 0; v < 16; ++v) *reinterpret_cast<f32x4*>(p + v * 4) = z;
    }
}

// ---------------- split-K MFMA kernel: 128x128, BK=64, 2-deep counted-vmcnt pipeline ----------------
// SESSION BEST (r24: trimm 67.4us / total 101.6us). XCD column grouping (FETCH 152->95MB),
// counted vmcnt(8) (never 0 in-loop), BK=64 (halved barriers/k-tile vs BK=32 = -10%; BK=128
// regressed: 1 block/CU lost cross-block overlap), conflict-free coalescing-preserving XOR
// swizzle (conflicts 3.06M->0). 64KB LDS -> 2 blocks/CU = measured optimum of the
// rendezvous-count vs residency tradeoff.
__global__ __launch_bounds__(256) void trimm_split(const ushort* __restrict__ Au,
                                                   const ushort* __restrict__ BTu,
                                                   float* __restrict__ C) {
    const int tid = threadIdx.x;
    const int xcd = blockIdx.x & 7;
    int slot = blockIdx.x >> 3;

    // ---- decode (xcd, slot) -> (bi, bj, chunk c of nch) ----
    const int cols[4] = {31 - xcd, 16 + xcd, 15 - xcd, xcd};   // work-descending
    int bj = -1;
    for (int ci = 0; ci < 4; ++ci) {
        int cj = cols[ci], n = col_jobs(cj);
        if (slot < n) { bj = cj; break; }
        slot -= n;
    }
    if (bj < 0) return;                           // idle slot (grid padding)

    int bi = 0, c = 0, nch = 1;
    for (int i = 0; i <= bj; ++i) {
        int nc = (bj - i + 8) >> 3;               // ceil((bj-i+1)/8)
        if (slot < nc) { bi = i; c = slot; nch = nc; break; }
        slot -= nc;
    }
    const int d = bj - bi;
    const int L = d + 1;                          // k-tiles of 128 in [bi, bj]
    const int kt0 = (c * L) / nch, kt1 = ((c + 1) * L) / nch;
    const int k_base = (bi + kt0) * 128;
    const int nsteps = (kt1 - kt0) * 2;           // BK=64 steps (always >= 2)

    __shared__ ushort lA[2][128 * 64];            // 2 x 16 KB
    __shared__ ushort lB[2][128 * 64];            // 2 x 16 KB  (64 KB total -> 2 blocks/CU)

    const int wid = tid >> 6, lane = tid & 63;
    const int wr = wid >> 1, wc = wid & 1;
    const int l16 = lane & 15, kh = lane >> 4;

    // staging: 1024 chunks/operand/stage; thread does g = q*256+tid, q=0..3, per operand.
    // chunk g -> LDS ushort offset g*8 (row=g>>3, slot=g&7); source kslot = (g&7)^((g>>3)&7)
    const int gq0 = 0 * 256 + tid, gq1 = 1 * 256 + tid, gq2 = 2 * 256 + tid, gq3 = 3 * 256 + tid;
#define KS(g) (((((g) & 7) ^ (((g) >> 3) & 7))) << 3)
#define RW(g) ((g) >> 3)
    const ushort* pA0 = Au  + (size_t)(bi * 128 + RW(gq0)) * NN + KS(gq0) + k_base;
    const ushort* pA1 = Au  + (size_t)(bi * 128 + RW(gq1)) * NN + KS(gq1) + k_base;
    const ushort* pA2 = Au  + (size_t)(bi * 128 + RW(gq2)) * NN + KS(gq2) + k_base;
    const ushort* pA3 = Au  + (size_t)(bi * 128 + RW(gq3)) * NN + KS(gq3) + k_base;
    const ushort* pB0 = BTu + (size_t)(bj * 128 + RW(gq0)) * NN + KS(gq0) + k_base;
    const ushort* pB1 = BTu + (size_t)(bj * 128 + RW(gq1)) * NN + KS(gq1) + k_base;
    const ushort* pB2 = BTu + (size_t)(bj * 128 + RW(gq2)) * NN + KS(gq2) + k_base;
    const ushort* pB3 = BTu + (size_t)(bj * 128 + RW(gq3)) * NN + KS(gq3) + k_base;
#undef KS
#undef RW
    const int lo0 = gq0 * 8, lo1 = gq1 * 8, lo2 = gq2 * 8, lo3 = gq3 * 8;

#define GLOAD(src, dst) __builtin_amdgcn_global_load_lds(                      \
        (const __attribute__((address_space(1))) void*)(src),                  \
        (__attribute__((address_space(3))) void*)(dst), 16, 0, 0)
#define STAGE(buf, off)                                                        \
    do {                                                                       \
        GLOAD(pA0 + (off), &lA[buf][lo0]); GLOAD(pA1 + (off), &lA[buf][lo1]);  \
        GLOAD(pA2 + (off), &lA[buf][lo2]); GLOAD(pA3 + (off), &lA[buf][lo3]);  \
        GLOAD(pB0 + (off), &lB[buf][lo0]); GLOAD(pB1 + (off), &lB[buf][lo1]);  \
        GLOAD(pB2 + (off), &lB[buf][lo2]); GLOAD(pB3 + (off), &lB[buf][lo3]);  \
    } while (0)

    f32x4 zero = {0.f, 0.f, 0.f, 0.f};
    f32x4 acc[4][4];
#pragma unroll
    for (int m = 0; m < 4; ++m)
#pragma unroll
        for (int n = 0; n < 4; ++n) acc[m][n] = zero;

    // prologue: 2 stages in flight (8 loads each)
    STAGE(0, 0);
    if (nsteps > 1) STAGE(1, 64);

    for (int t = 0; t < nsteps; ++t) {
        const int cur = t & 1;
        // wait for stage t only: stage t+1's 8 loads stay outstanding (counted vmcnt, never 0 in-loop)
        if (t + 1 < nsteps) asm volatile("s_waitcnt vmcnt(8)" ::: "memory");
        else                asm volatile("s_waitcnt vmcnt(0)" ::: "memory");
        __builtin_amdgcn_s_barrier();
        __builtin_amdgcn_sched_barrier(0);   // pin ds_reads below the barrier (cross-wave staging)

        // two K=32 halves from the same buffer (no barrier between: read-only)
#pragma unroll
        for (int h = 0; h < 2; ++h) {
            bf16x8 af[4], bfr[4];
#pragma unroll
            for (int m = 0; m < 4; ++m) {
                int row = wr * 64 + m * 16 + l16;
                af[m] = *reinterpret_cast<const bf16x8*>(
                    &lA[cur][row * 64 + (((h * 4 + kh) ^ (row & 7)) << 3)]);
            }
#pragma unroll
            for (int n = 0; n < 4; ++n) {
                int row = wc * 64 + n * 16 + l16;
                bfr[n] = *reinterpret_cast<const bf16x8*>(
                    &lB[cur][row * 64 + (((h * 4 + kh) ^ (row & 7)) << 3)]);
            }
#pragma unroll
            for (int m = 0; m < 4; ++m)
#pragma unroll
                for (int n = 0; n < 4; ++n)
                    acc[m][n] = __builtin_amdgcn_mfma_f32_16x16x32_bf16(af[m], bfr[n], acc[m][n], 0, 0, 0);
        }

        __builtin_amdgcn_s_barrier();        // all waves done reading buf[cur]
        __builtin_amdgcn_sched_barrier(0);   // pin the overwrite below the barrier
        if (t + 2 < nsteps) STAGE(cur, (t + 2) * 64);
    }
#undef STAGE
#undef GLOAD

    // C/D layout: col = lane&15, row = (lane>>4)*4 + reg
    if (nch == 1) {
#pragma unroll
        for (int m = 0; m < 4; ++m)
#pragma unroll
            for (int n = 0; n < 4; ++n) {
                int row = bi * 128 + wr * 64 + m * 16 + kh * 4;
                int col = bj * 128 + wc * 64 + n * 16 + l16;
#pragma unroll
                for (int r = 0; r < 4; ++r)
                    C[(size_t)(row + r) * NN + col] = acc[m][n][r];
            }
    } else {
#pragma unroll
        for (int m = 0; m < 4; ++m)
#pragma unroll
            for (int n = 0; n < 4; ++n) {
                int row = bi * 128 + wr * 64 + m * 16 + kh * 4;
                int col = bj * 128 + wc * 64 + n * 16 + l16;
#pragma unroll
                for (int r = 0; r < 4; ++r)
                    unsafeAtomicAdd(&C[(size_t)(row + r) * NN + col], acc[m][n][r]);
            }
    }
}

// ---------------- fp32 fallback (only if ws too small) ----------------
__global__ __launch_bounds__(256) void tri_fp32(const float* __restrict__ A,
                                                const float* __restrict__ B,
                                                float* __restrict__ C) {
    const int bi = blockIdx.y, bj = blockIdx.x, tid = threadIdx.x;
    const int r0 = (tid >> 4) << 2, c0 = (tid & 15) << 2;
    f32x4 z = {0.f, 0.f, 0.f, 0.f};
    if (bi > bj) {
#pragma unroll
        for (int r = 0; r < 4; ++r)
            *reinterpret_cast<f32x4*>(C + (size_t)(bi * 64 + r0 + r) * NN + bj * 64 + c0) = z;
        return;
    }
    __shared__ float As[64][65], Bs[64][65];
    float acc[4][4] = {};
    for (int kt = bi; kt <= bj; ++kt) {
        const int k0 = kt * 64;
#pragma unroll
        for (int q = 0; q < 4; ++q) {
            int g = q * 256 + tid, r = g >> 4, f4 = g & 15;
            f32x4 va = *reinterpret_cast<const f32x4*>(A + (size_t)(bi * 64 + r) * NN + k0 + f4 * 4);
            f32x4 vb = *reinterpret_cast<const f32x4*>(B + (size_t)(k0 + r) * NN + bj * 64 + f4 * 4);
#pragma unroll
            for (int j = 0; j < 4; ++j) {
                As[r][f4 * 4 + j] = (k0 + f4 * 4 + j >= bi * 64 + r) ? va[j] : 0.f;
                Bs[r][f4 * 4 + j] = (bj * 64 + f4 * 4 + j >= k0 + r) ? vb[j] : 0.f;
            }
        }
        __syncthreads();
        for (int kk = 0; kk < 64; ++kk) {
#pragma unroll
            for (int r = 0; r < 4; ++r) {
                float a = As[r0 + r][kk];
#pragma unroll
                for (int cc = 0; cc < 4; ++cc) acc[r][cc] += a * Bs[kk][c0 + cc];
            }
        }
        __syncthreads();
    }
#pragma unroll
    for (int r = 0; r < 4; ++r) {
        f32x4 o = {acc[r][0], acc[r][1], acc[r][2], acc[r][3]};
        *reinterpret_cast<f32x4*>(C + (size_t)(bi * 64 + r0 + r) * NN + bj * 64 + c0) = o;
    }
}

extern "C" void kernel_launch(void* const* d_in, const int* in_sizes, int n_in,
                              void* d_out, int out_size, void* d_ws, size_t ws_size,
                              hipStream_t stream) {
    const float* A = (const float*)d_in[0];
    const float* B = (const float*)d_in[1];
    float* C = (float*)d_out;

    const size_t need = (size_t)2 * NN * NN * sizeof(ushort);   // 64 MB
    if (ws_size >= need) {
        ushort* Au  = (ushort*)d_ws;
        ushort* BTu = Au + (size_t)NN * NN;
        prep<<<dim3(32, 32, 3), 256, 0, stream>>>(A, B, Au, BTu, C);
        trimm_split<<<GRID_TOT, 256, 0, stream>>>(Au, BTu, C);
    } else {
        tri_fp32<<<dim3(64, 64), 256, 0, stream>>>(A, B, C);
    }
}